// Round 2
// baseline (571.922 us; speedup 1.0000x reference)
//
#include <hip/hip_runtime.h>
#include <hip/hip_bf16.h>
#include <cstdint>

#define B_ 8
#define T_ 4096
#define D_ 768
#define H_ 12
#define M_ (B_*T_)          // 32768 rows
#define CHUNKS 256
#define CLEN 16             // CHUNKS*CLEN == T_
#define WELEM (D_*D_)       // 589824
#define NCH (B_*H_*64)      // 6144 scan channels

typedef __attribute__((ext_vector_type(8))) short bf16x8;
typedef __attribute__((ext_vector_type(4))) float f32x4;

static __device__ __forceinline__ unsigned short f2bf(float f) {
  __hip_bfloat16 h = __float2bfloat16(f);
  return __builtin_bit_cast(unsigned short, h);
}
static __device__ __forceinline__ float bf2f(unsigned short u) {
  unsigned v = ((unsigned)u) << 16;
  return __builtin_bit_cast(float, v);
}

static __device__ __forceinline__ void async16(const void* g, void* l) {
  __builtin_amdgcn_global_load_lds(
      (const __attribute__((address_space(1))) unsigned int*)g,
      (__attribute__((address_space(3))) unsigned int*)l, 16, 0, 0);
}

// ---------------- fallback: zero the output (ws too small diagnostic) ----------------
__global__ __launch_bounds__(256) void zero_out_kernel(float* __restrict__ out, size_t n4) {
  size_t gid = (size_t)blockIdx.x * 256 + threadIdx.x;
  if (gid < n4) *(float4*)(out + gid * 4) = make_float4(0.f, 0.f, 0.f, 0.f);
}

// ---------------- token-shift mix: xr/xk/xv (bf16) ----------------
__global__ __launch_bounds__(256) void mix_kernel(
    const float* __restrict__ x, const float* __restrict__ tmr,
    const float* __restrict__ tmk, const float* __restrict__ tmv,
    unsigned short* __restrict__ xr, unsigned short* __restrict__ xk,
    unsigned short* __restrict__ xv) {
  size_t gid = (size_t)blockIdx.x * 256 + threadIdx.x;
  size_t idx4 = gid * 4;
  int d = (int)(idx4 % D_);
  size_t row = idx4 / D_;
  int t = (int)(row & (T_ - 1));
  float4 xc = *(const float4*)(x + idx4);
  float4 xp = make_float4(0.f, 0.f, 0.f, 0.f);
  if (t > 0) xp = *(const float4*)(x + idx4 - D_);
  float4 mr = *(const float4*)(tmr + d);
  float4 mk = *(const float4*)(tmk + d);
  float4 mv = *(const float4*)(tmv + d);
  ushort4 orr, okk, ovv;
  orr.x = f2bf(xc.x*mr.x + xp.x*(1.f-mr.x));
  orr.y = f2bf(xc.y*mr.y + xp.y*(1.f-mr.y));
  orr.z = f2bf(xc.z*mr.z + xp.z*(1.f-mr.z));
  orr.w = f2bf(xc.w*mr.w + xp.w*(1.f-mr.w));
  okk.x = f2bf(xc.x*mk.x + xp.x*(1.f-mk.x));
  okk.y = f2bf(xc.y*mk.y + xp.y*(1.f-mk.y));
  okk.z = f2bf(xc.z*mk.z + xp.z*(1.f-mk.z));
  okk.w = f2bf(xc.w*mk.w + xp.w*(1.f-mk.w));
  ovv.x = f2bf(xc.x*mv.x + xp.x*(1.f-mv.x));
  ovv.y = f2bf(xc.y*mv.y + xp.y*(1.f-mv.y));
  ovv.z = f2bf(xc.z*mv.z + xp.z*(1.f-mv.z));
  ovv.w = f2bf(xc.w*mv.w + xp.w*(1.f-mv.w));
  *(ushort4*)(xr + idx4) = orr;
  *(ushort4*)(xk + idx4) = okk;
  *(ushort4*)(xv + idx4) = ovv;
}

// ---------------- weight fp32 -> bf16 (keeps [out,in] layout) ----------------
__global__ __launch_bounds__(256) void wconv_kernel(
    const float* __restrict__ a, const float* __restrict__ b,
    const float* __restrict__ c, const float* __restrict__ d,
    unsigned short* __restrict__ o) {
  size_t gid = (size_t)blockIdx.x * 256 + threadIdx.x;
  size_t idx4 = gid * 4;
  size_t mi = idx4 / WELEM;
  size_t off = idx4 % WELEM;
  const float* src = (mi == 0) ? a : (mi == 1) ? b : (mi == 2) ? c : d;
  float4 v = *(const float4*)(src + off);
  ushort4 u;
  u.x = f2bf(v.x); u.y = f2bf(v.y); u.z = f2bf(v.z); u.w = f2bf(v.w);
  *(ushort4*)(o + idx4) = u;
}

// ---- GEMM: C[M,N] = A[M,K] @ Bw[N,K]^T. ACT: 1=sigmoid. OBF: 1=bf16 out, 0=fp32 out ----
// 128x128 tile, BK=64, 2-phase double-buffered prefetch (T3-min): issue next K-tile's
// global_load_lds BEFORE ds_read+MFMA of current tile; one drain+barrier per K-step.
// XOR-swizzled LDS both-sides, XCD-chunked block swizzle, LDS-staged bf16 epilogue.
template<int ACT, int OBF>
__global__ __launch_bounds__(256) void gemm_nt(
    const unsigned short* __restrict__ A,
    const unsigned short* __restrict__ Bw,
    void* __restrict__ Cv, int M, int N, int Kd) {
  __shared__ __align__(16) unsigned short smem[2][128 * 128];   // 2 x 32 KB
  const int tid = threadIdx.x;
  const int wave = tid >> 6, lane = tid & 63;
  const int quad = lane >> 4, l16 = lane & 15;

  // XCD-aware chunked swizzle (bijective even when nwg % 8 != 0)
  int nwg = gridDim.x * gridDim.y;
  int lin = blockIdx.y * gridDim.x + blockIdx.x;
  int q = nwg >> 3, r = nwg & 7;
  int xcd = lin & 7, off = lin >> 3;
  int swz = (xcd < r ? xcd * (q + 1) : r * (q + 1) + (xcd - r) * q) + off;
  const int m0 = (swz / gridDim.x) * 128;
  const int n0 = (swz % gridDim.x) * 128;
  const int wm = (wave & 1) * 64, wn = (wave >> 1) * 64;

  auto stage = [&](int buf, int kb) {
    unsigned short* As = smem[buf];
    unsigned short* Bs = smem[buf] + 128 * 64;
#pragma unroll
    for (int j = 0; j < 4; ++j) {
      int chunk = j * 256 + tid;           // 0..1023 16B-granules per tile
      int row = chunk >> 3, slot = chunk & 7;
      int ks = slot ^ (row & 7);           // pre-swizzled global source granule
      async16(A  + ((size_t)(m0 + row) * Kd + kb + ks * 8), &As[chunk * 8]);
      async16(Bw + ((size_t)(n0 + row) * Kd + kb + ks * 8), &Bs[chunk * 8]);
    }
  };

  f32x4 acc[4][4] = {};

  stage(0, 0);                 // prologue: first tile in flight (covers acc init)
  __syncthreads();             // drains vmcnt(0): buf0 ready
  int cur = 0;
  for (int kb = 0; kb < Kd; kb += 64) {
    if (kb + 64 < Kd) stage(cur ^ 1, kb + 64);   // issue next tile EARLY
    const unsigned short* As = smem[cur];
    const unsigned short* Bs = smem[cur] + 128 * 64;
#pragma unroll
    for (int kk = 0; kk < 2; ++kk) {
      bf16x8 a[4], b[4];
#pragma unroll
      for (int i = 0; i < 4; ++i) {
        int ra = wm + i * 16 + l16;
        a[i] = *(const bf16x8*)&As[ra * 64 + (((kk * 4 + quad) ^ (ra & 7)) * 8)];
        int rb = wn + i * 16 + l16;
        b[i] = *(const bf16x8*)&Bs[rb * 64 + (((kk * 4 + quad) ^ (rb & 7)) * 8)];
      }
#pragma unroll
      for (int i = 0; i < 4; ++i)
#pragma unroll
        for (int jj = 0; jj < 4; ++jj)
          acc[i][jj] = __builtin_amdgcn_mfma_f32_16x16x32_bf16(a[i], b[jj], acc[i][jj], 0, 0, 0);
    }
    __syncthreads();           // drains vmcnt: next buf ready; cur reads done
    cur ^= 1;
  }

  if (OBF) {
    // LDS-staged epilogue: full 64B-line ushort8 stores
    unsigned short* Cs = smem[0];          // [128][128] bf16, granule-XOR swizzled
#pragma unroll
    for (int i = 0; i < 4; ++i) {
#pragma unroll
      for (int jj = 0; jj < 4; ++jj) {
        int col = wn + jj * 16 + l16;
#pragma unroll
        for (int rr = 0; rr < 4; ++rr) {
          int row = wm + i * 16 + quad * 4 + rr;
          float v = acc[i][jj][rr];
          if (ACT == 1) v = 1.f / (1.f + __expf(-v));
          int cg = (col >> 3) ^ (row & 7);
          Cs[row * 128 + cg * 8 + (col & 7)] = f2bf(v);
        }
      }
    }
    __syncthreads();
#pragma unroll
    for (int g = 0; g < 8; ++g) {
      int gi = g * 256 + tid;              // 0..2047: 128 rows x 16 granules
      int row = gi >> 4, cg = gi & 15;
      int sg = cg ^ (row & 7);
      bf16x8 vv = *(const bf16x8*)&Cs[row * 128 + sg * 8];
      *(bf16x8*)((unsigned short*)Cv + (size_t)(m0 + row) * N + n0 + cg * 8) = vv;
    }
  } else {
    // fp32 out: quad-row 64B segments are already full lines
#pragma unroll
    for (int i = 0; i < 4; ++i) {
      int rowb = m0 + wm + i * 16 + quad * 4;
#pragma unroll
      for (int jj = 0; jj < 4; ++jj) {
        int col = n0 + wn + jj * 16 + l16;
#pragma unroll
        for (int rr = 0; rr < 4; ++rr) {
          float v = acc[i][jj][rr];
          ((float*)Cv)[(size_t)(rowb + rr) * N + col] = v;
        }
      }
    }
  }
}

// ---------------- WKV pass 1: per-chunk local scan, 8 channels/thread ----------------
__global__ __launch_bounds__(256) void wkv_pass1(
    const unsigned short* __restrict__ Kb, const unsigned short* __restrict__ Vb,
    const float* __restrict__ td,
    float* __restrict__ sumN, float* __restrict__ sumD) {
  int gid = blockIdx.x * 256 + threadIdx.x;   // ((c*B + b)*H + h)*8 + kg
  int kg = gid & 7;
  int tmp = gid >> 3;
  int h = tmp % H_;
  tmp /= H_;
  int b = tmp % B_;
  int c = tmp / B_;
  const float* tdp = td + h * 64 + kg * 8;
  float w[8], num[8], den[8];
#pragma unroll
  for (int j = 0; j < 8; ++j) {
    w[j] = __expf(-__expf(tdp[j]));
    num[j] = 0.f; den[j] = 0.f;
  }
  size_t base = ((size_t)(b * T_ + c * CLEN)) * D_ + h * 64 + kg * 8;
#pragma unroll 4
  for (int i = 0; i < CLEN; ++i) {
    bf16x8 k8 = *(const bf16x8*)(Kb + base + (size_t)i * D_);
    bf16x8 v8 = *(const bf16x8*)(Vb + base + (size_t)i * D_);
#pragma unroll
    for (int j = 0; j < 8; ++j) {
      float ek = __expf(bf2f((unsigned short)k8[j]));
      num[j] = num[j] * w[j] + ek * bf2f((unsigned short)v8[j]);
      den[j] = den[j] * w[j] + ek;
    }
  }
  int ob = ((c * B_ + b) * H_ + h) * 64 + kg * 8;
  *(float4*)(sumN + ob)     = make_float4(num[0], num[1], num[2], num[3]);
  *(float4*)(sumN + ob + 4) = make_float4(num[4], num[5], num[6], num[7]);
  *(float4*)(sumD + ob)     = make_float4(den[0], den[1], den[2], den[3]);
  *(float4*)(sumD + ob + 4) = make_float4(den[4], den[5], den[6], den[7]);
}

// ------- WKV pass 2: inter-chunk exclusive prefix — PARALLEL segmented scan -------
// One block per channel; 256 threads = 256 chunks; Hillis-Steele over (decay, n, d).
__global__ __launch_bounds__(256) void wkv_pass2(
    const float* __restrict__ sumN, const float* __restrict__ sumD,
    const float* __restrict__ td,
    float* __restrict__ prefN, float* __restrict__ prefD,
    float* __restrict__ gstats) {
  int ch = blockIdx.x;                    // (b*H + h)*64 + k, < 6144
  int c = threadIdx.x;                    // chunk index
  if (ch == 0 && c < 192) gstats[c] = 0.f;
  int k = ch & 63;
  int h = (ch >> 6) % H_;
  float w = __expf(-__expf(td[h * 64 + k]));
  float wL = w;
#pragma unroll
  for (int i = 0; i < 4; ++i) wL *= wL;   // w^16 (= w^CLEN)
  __shared__ float Aa[256], Nn[256], Dd[256];
  int j = c * NCH + ch;
  float a = wL, n = sumN[j], d = sumD[j];
  Aa[c] = a; Nn[c] = n; Dd[c] = d;
  __syncthreads();
  // inclusive scan: combine(L,R) = (aL*aR, nL*aR + nR, dL*aR + dR)
  for (int off = 1; off < 256; off <<= 1) {
    float aL = 0.f, nL = 0.f, dL = 0.f;
    if (c >= off) { aL = Aa[c - off]; nL = Nn[c - off]; dL = Dd[c - off]; }
    __syncthreads();
    if (c >= off) {
      n = nL * a + n;
      d = dL * a + d;
      a = aL * a;
      Aa[c] = a; Nn[c] = n; Dd[c] = d;
    }
    __syncthreads();
  }
  // exclusive result for chunk c = inclusive of c-1
  float pn = 0.f, pd = 0.f;
  if (c > 0) { pn = Nn[c - 1]; pd = Dd[c - 1]; }
  prefN[j] = pn; prefD[j] = pd;
}

// --- WKV pass 3: wkv + y=r*wkv (in-place over r, bf16) + GN partial sums; 8 ch/thread ---
__global__ __launch_bounds__(256) void wkv_pass3(
    const unsigned short* __restrict__ Kb, const unsigned short* __restrict__ Vb,
    unsigned short* __restrict__ RY,
    const float* __restrict__ td, const float* __restrict__ tf,
    const float* __restrict__ prefN, const float* __restrict__ prefD,
    float* __restrict__ gsum, float* __restrict__ gsq) {
  int gid = blockIdx.x * 256 + threadIdx.x;   // ((c*B + b)*H + h)*8 + kg
  int kg = gid & 7;
  int tmp = gid >> 3;
  int h = tmp % H_;
  tmp /= H_;
  int b = tmp % B_;
  int c = tmp / B_;
  const float* tdp = td + h * 64 + kg * 8;
  const float* tfp = tf + h * 64 + kg * 8;
  float w[8], eu[8], num[8], den[8];
  int sb = ((c * B_ + b) * H_ + h) * 64 + kg * 8;
  float4 n0 = *(const float4*)(prefN + sb), n1 = *(const float4*)(prefN + sb + 4);
  float4 d0 = *(const float4*)(prefD + sb), d1 = *(const float4*)(prefD + sb + 4);
  num[0]=n0.x; num[1]=n0.y; num[2]=n0.z; num[3]=n0.w;
  num[4]=n1.x; num[5]=n1.y; num[6]=n1.z; num[7]=n1.w;
  den[0]=d0.x; den[1]=d0.y; den[2]=d0.z; den[3]=d0.w;
  den[4]=d1.x; den[5]=d1.y; den[6]=d1.z; den[7]=d1.w;
#pragma unroll
  for (int j = 0; j < 8; ++j) {
    w[j]  = __expf(-__expf(tdp[j]));
    eu[j] = __expf(tfp[j]);
  }
  size_t base = ((size_t)(b * T_ + c * CLEN)) * D_ + h * 64 + kg * 8;
  float s1 = 0.f, s2 = 0.f;
#pragma unroll 4
  for (int i = 0; i < CLEN; ++i) {
    size_t idx = base + (size_t)i * D_;
    bf16x8 k8 = *(const bf16x8*)(Kb + idx);
    bf16x8 v8 = *(const bf16x8*)(Vb + idx);
    bf16x8 r8 = *(const bf16x8*)(RY + idx);
    bf16x8 y8;
#pragma unroll
    for (int j = 0; j < 8; ++j) {
      float kk = bf2f((unsigned short)k8[j]);
      float vv = bf2f((unsigned short)v8[j]);
      float rr = bf2f((unsigned short)r8[j]);
      float ek = __expf(kk);
      float wkv = __fdividef(num[j] + eu[j] * ek * vv, den[j] + eu[j] * ek + 1e-9f);
      unsigned short ybf = f2bf(rr * wkv);
      y8[j] = (short)ybf;
      float y = bf2f(ybf);                 // stats on the stored (rounded) value
      s1 += y; s2 += y * y;
      num[j] = num[j] * w[j] + ek * vv;
      den[j] = den[j] * w[j] + ek;
    }
    *(bf16x8*)(RY + idx) = y8;
  }
  // reduce over the 8 lanes covering one head (kg = 0..7 are consecutive lanes)
#pragma unroll
  for (int off = 4; off; off >>= 1) {
    s1 += __shfl_xor(s1, off);
    s2 += __shfl_xor(s2, off);
  }
  if (kg == 0) {
    atomicAdd(&gsum[b * H_ + h], s1);
    atomicAdd(&gsq [b * H_ + h], s2);
  }
}

// ---------------- GroupNorm normalize (bf16 in) + bf16 out ----------------
__global__ __launch_bounds__(256) void gn_kernel(
    const unsigned short* __restrict__ Y, const float* __restrict__ gsum,
    const float* __restrict__ gsq, const float* __restrict__ gw,
    const float* __restrict__ gb, unsigned short* __restrict__ Ybf) {
  size_t gid = (size_t)blockIdx.x * 256 + threadIdx.x;
  size_t idx4 = gid * 4;
  int d = (int)(idx4 % D_);
  size_t row = idx4 / D_;
  int b = (int)(row >> 12);          // T = 4096
  int h = d >> 6;
  int g = b * H_ + h;
  const float inv = 1.f / (float)(T_ * 64);
  float mean = gsum[g] * inv;
  float var = gsq[g] * inv - mean * mean;
  float rstd = rsqrtf(var + 1e-5f);
  ushort4 yu = *(const ushort4*)(Y + idx4);
  float4 wv = *(const float4*)(gw + d);
  float4 bv = *(const float4*)(gb + d);
  ushort4 o;
  o.x = f2bf((bf2f(yu.x) - mean) * rstd * wv.x + bv.x);
  o.y = f2bf((bf2f(yu.y) - mean) * rstd * wv.y + bv.y);
  o.z = f2bf((bf2f(yu.z) - mean) * rstd * wv.z + bv.z);
  o.w = f2bf((bf2f(yu.w) - mean) * rstd * wv.w + bv.w);
  *(ushort4*)(Ybf + idx4) = o;
}

extern "C" void kernel_launch(void* const* d_in, const int* in_sizes, int n_in,
                              void* d_out, int out_size, void* d_ws, size_t ws_size,
                              hipStream_t stream) {
  (void)in_sizes; (void)n_in;
  const float* x   = (const float*)d_in[0];
  const float* tmr = (const float*)d_in[1];
  const float* tmk = (const float*)d_in[2];
  const float* tmv = (const float*)d_in[3];
  const float* td  = (const float*)d_in[4];
  const float* tf  = (const float*)d_in[5];
  const float* Wr  = (const float*)d_in[6];
  const float* Wk  = (const float*)d_in[7];
  const float* Wv  = (const float*)d_in[8];
  const float* Wo  = (const float*)d_in[9];
  const float* gw  = (const float*)d_in[10];
  const float* gb  = (const float*)d_in[11];
  float* out = (float*)d_out;

  constexpr size_t MD = (size_t)M_ * D_;
  constexpr size_t NEED = 4 * (MD * 2)              // XR, XK, XV, Rb (bf16)
                        + (size_t)4 * WELEM * 2     // Wb
                        + 4 * ((size_t)CHUNKS * NCH * 4)  // sumN/sumD/prefN/prefD
                        + 1024;                     // gstats
  if (ws_size < NEED) {
    // diagnostic fallback: ws too small — produce zeros instead of faulting
    zero_out_kernel<<<(int)((MD / 4 + 255) / 256), 256, 0, stream>>>(out, MD / 4);
    return;
  }

  char* ws = (char*)d_ws;
  unsigned short* XR = (unsigned short*)ws; ws += MD * 2;
  unsigned short* XK = (unsigned short*)ws; ws += MD * 2;
  unsigned short* XV = (unsigned short*)ws; ws += MD * 2;
  unsigned short* Rb = (unsigned short*)ws; ws += MD * 2;
  unsigned short* Wb = (unsigned short*)ws; ws += (size_t)4 * WELEM * 2;
  float* sumN  = (float*)ws; ws += (size_t)CHUNKS * NCH * 4;
  float* sumD  = (float*)ws; ws += (size_t)CHUNKS * NCH * 4;
  float* prefN = (float*)ws; ws += (size_t)CHUNKS * NCH * 4;
  float* prefD = (float*)ws; ws += (size_t)CHUNKS * NCH * 4;
  float* gstats = (float*)ws; ws += 1024;
  // aliases onto dead buffers (dataflow-checked):
  unsigned short* Kb = XR;   // XR dead after gemm-r
  unsigned short* Vb = XK;   // XK dead after gemm-k
  unsigned short* Yb = XV;   // XV dead after gemm-v

  mix_kernel<<<(int)(MD / 1024), 256, 0, stream>>>(x, tmr, tmk, tmv, XR, XK, XV);
  wconv_kernel<<<(4 * WELEM / 4) / 256, 256, 0, stream>>>(Wr, Wk, Wv, Wo, Wb);

  dim3 ggrid(D_ / 128, M_ / 128);
  gemm_nt<1, 1><<<ggrid, 256, 0, stream>>>(XR, Wb,             Rb, M_, D_, D_);
  gemm_nt<0, 1><<<ggrid, 256, 0, stream>>>(XK, Wb + WELEM,     Kb, M_, D_, D_);
  gemm_nt<0, 1><<<ggrid, 256, 0, stream>>>(XV, Wb + 2 * WELEM, Vb, M_, D_, D_);

  wkv_pass1<<<(CHUNKS * NCH / 8) / 256, 256, 0, stream>>>(Kb, Vb, td, sumN, sumD);
  wkv_pass2<<<NCH, 256, 0, stream>>>(sumN, sumD, td, prefN, prefD, gstats);
  wkv_pass3<<<(CHUNKS * NCH / 8) / 256, 256, 0, stream>>>(Kb, Vb, Rb, td, tf,
                                                          prefN, prefD, gstats, gstats + 96);
  gn_kernel<<<(int)(MD / 1024), 256, 0, stream>>>(Rb, gstats, gstats + 96, gw, gb, Yb);

  gemm_nt<0, 0><<<ggrid, 256, 0, stream>>>(Yb, Wb + 3 * WELEM, out, M_, D_, D_);
}

// Round 3
// 538.596 us; speedup vs baseline: 1.0619x; 1.0619x over previous
//
#include <hip/hip_runtime.h>
#include <hip/hip_bf16.h>
#include <cstdint>

#define B_ 8
#define T_ 4096
#define D_ 768
#define H_ 12
#define M_ (B_*T_)          // 32768 rows
#define CHUNKS 256
#define CLEN 16             // CHUNKS*CLEN == T_
#define WELEM (D_*D_)       // 589824
#define NCH (B_*H_*64)      // 6144 scan channels

typedef __attribute__((ext_vector_type(8))) short bf16x8;
typedef __attribute__((ext_vector_type(4))) float f32x4;

static __device__ __forceinline__ unsigned short f2bf(float f) {
  __hip_bfloat16 h = __float2bfloat16(f);
  return __builtin_bit_cast(unsigned short, h);
}
static __device__ __forceinline__ float bf2f(unsigned short u) {
  unsigned v = ((unsigned)u) << 16;
  return __builtin_bit_cast(float, v);
}

static __device__ __forceinline__ void async16(const void* g, void* l) {
  __builtin_amdgcn_global_load_lds(
      (const __attribute__((address_space(1))) unsigned int*)g,
      (__attribute__((address_space(3))) unsigned int*)l, 16, 0, 0);
}

// ---------------- fallback: zero the output (ws too small diagnostic) ----------------
__global__ __launch_bounds__(256) void zero_out_kernel(float* __restrict__ out, size_t n4) {
  size_t gid = (size_t)blockIdx.x * 256 + threadIdx.x;
  if (gid < n4) *(float4*)(out + gid * 4) = make_float4(0.f, 0.f, 0.f, 0.f);
}

// ---------------- token-shift mix: xr/xk/xv (bf16) ----------------
__global__ __launch_bounds__(256) void mix_kernel(
    const float* __restrict__ x, const float* __restrict__ tmr,
    const float* __restrict__ tmk, const float* __restrict__ tmv,
    unsigned short* __restrict__ xr, unsigned short* __restrict__ xk,
    unsigned short* __restrict__ xv) {
  size_t gid = (size_t)blockIdx.x * 256 + threadIdx.x;
  size_t idx4 = gid * 4;
  int d = (int)(idx4 % D_);
  size_t row = idx4 / D_;
  int t = (int)(row & (T_ - 1));
  float4 xc = *(const float4*)(x + idx4);
  float4 xp = make_float4(0.f, 0.f, 0.f, 0.f);
  if (t > 0) xp = *(const float4*)(x + idx4 - D_);
  float4 mr = *(const float4*)(tmr + d);
  float4 mk = *(const float4*)(tmk + d);
  float4 mv = *(const float4*)(tmv + d);
  ushort4 orr, okk, ovv;
  orr.x = f2bf(xc.x*mr.x + xp.x*(1.f-mr.x));
  orr.y = f2bf(xc.y*mr.y + xp.y*(1.f-mr.y));
  orr.z = f2bf(xc.z*mr.z + xp.z*(1.f-mr.z));
  orr.w = f2bf(xc.w*mr.w + xp.w*(1.f-mr.w));
  okk.x = f2bf(xc.x*mk.x + xp.x*(1.f-mk.x));
  okk.y = f2bf(xc.y*mk.y + xp.y*(1.f-mk.y));
  okk.z = f2bf(xc.z*mk.z + xp.z*(1.f-mk.z));
  okk.w = f2bf(xc.w*mk.w + xp.w*(1.f-mk.w));
  ovv.x = f2bf(xc.x*mv.x + xp.x*(1.f-mv.x));
  ovv.y = f2bf(xc.y*mv.y + xp.y*(1.f-mv.y));
  ovv.z = f2bf(xc.z*mv.z + xp.z*(1.f-mv.z));
  ovv.w = f2bf(xc.w*mv.w + xp.w*(1.f-mv.w));
  *(ushort4*)(xr + idx4) = orr;
  *(ushort4*)(xk + idx4) = okk;
  *(ushort4*)(xv + idx4) = ovv;
}

// ---------------- weight fp32 -> bf16 (keeps [out,in] layout) ----------------
__global__ __launch_bounds__(256) void wconv_kernel(
    const float* __restrict__ a, const float* __restrict__ b,
    const float* __restrict__ c, const float* __restrict__ d,
    unsigned short* __restrict__ o) {
  size_t gid = (size_t)blockIdx.x * 256 + threadIdx.x;
  size_t idx4 = gid * 4;
  size_t mi = idx4 / WELEM;
  size_t off = idx4 % WELEM;
  const float* src = (mi == 0) ? a : (mi == 1) ? b : (mi == 2) ? c : d;
  float4 v = *(const float4*)(src + off);
  ushort4 u;
  u.x = f2bf(v.x); u.y = f2bf(v.y); u.z = f2bf(v.z); u.w = f2bf(v.w);
  *(ushort4*)(o + idx4) = u;
}

// ---- GEMM: C[M,N] = A[M,K] @ Bw[N,K]^T. ACT: 1=sigmoid. OBF: 1=bf16 out, 0=fp32 out ----
// 128x128 tile, BK=32, depth-4 software pipeline with COUNTED vmcnt + raw s_barrier
// (loads stay in flight across barriers — T3+T4). XOR-swizzled LDS (granule ^ (row>>1)&3),
// XCD-chunked block swizzle, LDS-staged bf16 epilogue for full-line writes.
template<int ACT, int OBF>
__global__ __launch_bounds__(256) void gemm_nt(
    const unsigned short* __restrict__ A,
    const unsigned short* __restrict__ Bw,
    void* __restrict__ Cv, int M, int N, int Kd) {
  __shared__ __align__(16) unsigned short smem[4][128 * 64];   // 4 stages x 16KB = 64KB
  const int tid = threadIdx.x;
  const int wave = tid >> 6, lane = tid & 63;
  const int quad = lane >> 4, l16 = lane & 15;

  // XCD-aware chunked swizzle (bijective even when nwg % 8 != 0)
  int nwg = gridDim.x * gridDim.y;
  int lin = blockIdx.y * gridDim.x + blockIdx.x;
  int q = nwg >> 3, r = nwg & 7;
  int xcd = lin & 7, off = lin >> 3;
  int swz = (xcd < r ? xcd * (q + 1) : r * (q + 1) + (xcd - r) * q) + off;
  const int m0 = (swz / gridDim.x) * 128;
  const int n0 = (swz % gridDim.x) * 128;
  const int wm = (wave & 1) * 64, wn = (wave >> 1) * 64;

  // stage one BK=32 tile (A:128x32 + B:128x32 bf16) into buffer buf.
  // 512 granules(16B) each; thread does 2 for A + 2 for B = 4 VMEM instr/wave.
  auto stage = [&](int buf, int kb) {
    unsigned short* As = smem[buf];
    unsigned short* Bs = smem[buf] + 128 * 32;
#pragma unroll
    for (int j = 0; j < 2; ++j) {
      int chunk = j * 256 + tid;           // 0..511
      int row = chunk >> 2, slot = chunk & 3;
      int ks = slot ^ ((row >> 1) & 3);    // pre-swizzled global source granule
      async16(A  + ((size_t)(m0 + row) * Kd + kb + ks * 8), &As[chunk * 8]);
      async16(Bw + ((size_t)(n0 + row) * Kd + kb + ks * 8), &Bs[chunk * 8]);
    }
  };

  f32x4 acc[4][4] = {};
  const int NT = Kd >> 5;                  // 24 K-tiles

  stage(0, 0); stage(1, 32); stage(2, 64); // 12 VMEM in flight
  for (int t = 0; t < NT; ++t) {
    // wait for MY portion of tile t (leave up to 2 younger stages in flight),
    // then barrier publishes: all waves' tile-t loads landed AND all reads of
    // the buffer we are about to overwrite are complete.
    if (t < NT - 2)       asm volatile("s_waitcnt vmcnt(8)" ::: "memory");
    else if (t == NT - 2) asm volatile("s_waitcnt vmcnt(4)" ::: "memory");
    else                  asm volatile("s_waitcnt vmcnt(0)" ::: "memory");
    __builtin_amdgcn_s_barrier();
    if (t + 3 < NT) stage((t + 3) & 3, (t + 3) * 32);   // into buf (t-1)%4: free
    const unsigned short* As = smem[t & 3];
    const unsigned short* Bs = smem[t & 3] + 128 * 32;
    bf16x8 a[4], b[4];
#pragma unroll
    for (int i = 0; i < 4; ++i) {
      int ra = wm + i * 16 + l16;
      a[i] = *(const bf16x8*)&As[ra * 32 + ((quad ^ ((ra >> 1) & 3)) * 8)];
      int rb = wn + i * 16 + l16;
      b[i] = *(const bf16x8*)&Bs[rb * 32 + ((quad ^ ((rb >> 1) & 3)) * 8)];
    }
#pragma unroll
    for (int i = 0; i < 4; ++i)
#pragma unroll
      for (int jj = 0; jj < 4; ++jj)
        acc[i][jj] = __builtin_amdgcn_mfma_f32_16x16x32_bf16(a[i], b[jj], acc[i][jj], 0, 0, 0);
    // reads complete before MFMA (compiler lgkm deps) -> before next barrier.
  }

  if (OBF) {
    // LDS-staged epilogue: full 64B-line ushort8 stores
    unsigned short* Cs = (unsigned short*)smem;  // [128][128] bf16, granule-XOR swizzled
#pragma unroll
    for (int i = 0; i < 4; ++i) {
#pragma unroll
      for (int jj = 0; jj < 4; ++jj) {
        int col = wn + jj * 16 + l16;
#pragma unroll
        for (int rr = 0; rr < 4; ++rr) {
          int row = wm + i * 16 + quad * 4 + rr;
          float v = acc[i][jj][rr];
          if (ACT == 1) v = 1.f / (1.f + __expf(-v));
          int cg = (col >> 3) ^ (row & 7);
          Cs[row * 128 + cg * 8 + (col & 7)] = f2bf(v);
        }
      }
    }
    __syncthreads();
#pragma unroll
    for (int g = 0; g < 8; ++g) {
      int gi = g * 256 + tid;              // 0..2047: 128 rows x 16 granules
      int row = gi >> 4, cg = gi & 15;
      int sg = cg ^ (row & 7);
      bf16x8 vv = *(const bf16x8*)&Cs[row * 128 + sg * 8];
      *(bf16x8*)((unsigned short*)Cv + (size_t)(m0 + row) * N + n0 + cg * 8) = vv;
    }
  } else {
    // fp32 out: quad-row 64B segments are already full lines
#pragma unroll
    for (int i = 0; i < 4; ++i) {
      int rowb = m0 + wm + i * 16 + quad * 4;
#pragma unroll
      for (int jj = 0; jj < 4; ++jj) {
        int col = n0 + wn + jj * 16 + l16;
#pragma unroll
        for (int rr = 0; rr < 4; ++rr) {
          float v = acc[i][jj][rr];
          ((float*)Cv)[(size_t)(rowb + rr) * N + col] = v;
        }
      }
    }
  }
}

// ---------------- WKV pass 1: per-chunk local scan, 8 channels/thread ----------------
__global__ __launch_bounds__(256) void wkv_pass1(
    const unsigned short* __restrict__ Kb, const unsigned short* __restrict__ Vb,
    const float* __restrict__ td,
    float* __restrict__ sumN, float* __restrict__ sumD) {
  int gid = blockIdx.x * 256 + threadIdx.x;   // ((c*B + b)*H + h)*8 + kg
  int kg = gid & 7;
  int tmp = gid >> 3;
  int h = tmp % H_;
  tmp /= H_;
  int b = tmp % B_;
  int c = tmp / B_;
  const float* tdp = td + h * 64 + kg * 8;
  float w[8], num[8], den[8];
#pragma unroll
  for (int j = 0; j < 8; ++j) {
    w[j] = __expf(-__expf(tdp[j]));
    num[j] = 0.f; den[j] = 0.f;
  }
  size_t base = ((size_t)(b * T_ + c * CLEN)) * D_ + h * 64 + kg * 8;
#pragma unroll 4
  for (int i = 0; i < CLEN; ++i) {
    bf16x8 k8 = *(const bf16x8*)(Kb + base + (size_t)i * D_);
    bf16x8 v8 = *(const bf16x8*)(Vb + base + (size_t)i * D_);
#pragma unroll
    for (int j = 0; j < 8; ++j) {
      float ek = __expf(bf2f((unsigned short)k8[j]));
      num[j] = num[j] * w[j] + ek * bf2f((unsigned short)v8[j]);
      den[j] = den[j] * w[j] + ek;
    }
  }
  int ob = ((c * B_ + b) * H_ + h) * 64 + kg * 8;
  *(float4*)(sumN + ob)     = make_float4(num[0], num[1], num[2], num[3]);
  *(float4*)(sumN + ob + 4) = make_float4(num[4], num[5], num[6], num[7]);
  *(float4*)(sumD + ob)     = make_float4(den[0], den[1], den[2], den[3]);
  *(float4*)(sumD + ob + 4) = make_float4(den[4], den[5], den[6], den[7]);
}

// ------- WKV pass 2: inter-chunk exclusive prefix — coalesced LDS-transposed scan -------
// 192 blocks: one per (b,h) x {N,D}. Block loads [256 chunks][64 ch] f32 tile (64KB),
// scans along chunks in LDS (4 row-groups, serial in-group + cross-group carry),
// writes exclusive prefixes coalesced.
__global__ __launch_bounds__(256) void wkv_pass2(
    const float* __restrict__ sumN, const float* __restrict__ sumD,
    const float* __restrict__ td,
    float* __restrict__ prefN, float* __restrict__ prefD,
    float* __restrict__ gstats) {
  __shared__ float tile[256][64];           // 64KB
  int bid = blockIdx.x;                     // [0,192)
  if (bid == 0 && threadIdx.x < 192) gstats[threadIdx.x] = 0.f;
  int bh = bid >> 1, qd = bid & 1;
  const float* src = qd ? sumD : sumN;
  float* dst = qd ? prefD : prefN;
  int h = bh % H_;
  int base = bh * 64;                       // channel base within NCH
  int t = threadIdx.x;
  { // load: 16 rows x float4 per thread, coalesced
    int c4 = (t & 15) * 4;
    int rg = t >> 4;
#pragma unroll 4
    for (int i = 0; i < 16; ++i) {
      int row = rg * 16 + i;
      *(float4*)&tile[row][c4] = *(const float4*)&src[(size_t)row * NCH + base + c4];
    }
  }
  __syncthreads();
  int ch = t & 63, g = t >> 6;              // 4 groups x 64 rows
  float w = __expf(-__expf(td[h * 64 + ch]));
  float wL = w;
#pragma unroll
  for (int i = 0; i < 4; ++i) wL *= wL;     // w^16 (= w^CLEN)
  // serial inclusive scan within group, in place (bank: ch%32, 2-way = free)
  float v = 0.f;
  for (int i = 0; i < 64; ++i) {
    int row = g * 64 + i;
    v = v * wL + tile[row][ch];
    tile[row][ch] = v;
  }
  __syncthreads();
  // cross-group carry E_g = global inclusive at end of group g-1
  float wL64 = wL;
#pragma unroll
  for (int i = 0; i < 6; ++i) wL64 *= wL64; // wL^64
  float E = 0.f;
  for (int gp = 0; gp < g; ++gp)            // g is wave-uniform
    E = E * wL64 + tile[gp * 64 + 63][ch];
  // exclusive prefix: P[g*64] = E; P[g*64+i] = I_local[i-1] + E*wL^i
  float f = 1.f;
  for (int i = 0; i < 64; ++i) {
    int row = g * 64 + i;
    float P = (i == 0) ? E : tile[row - 1][ch] + E * f;
    dst[(size_t)row * NCH + base + ch] = P;
    f *= wL;
  }
}

// --- WKV pass 3: wkv + y=r*wkv (in-place over r, bf16) + GN partial sums; 8 ch/thread ---
__global__ __launch_bounds__(256) void wkv_pass3(
    const unsigned short* __restrict__ Kb, const unsigned short* __restrict__ Vb,
    unsigned short* __restrict__ RY,
    const float* __restrict__ td, const float* __restrict__ tf,
    const float* __restrict__ prefN, const float* __restrict__ prefD,
    float* __restrict__ gsum, float* __restrict__ gsq) {
  int gid = blockIdx.x * 256 + threadIdx.x;   // ((c*B + b)*H + h)*8 + kg
  int kg = gid & 7;
  int tmp = gid >> 3;
  int h = tmp % H_;
  tmp /= H_;
  int b = tmp % B_;
  int c = tmp / B_;
  const float* tdp = td + h * 64 + kg * 8;
  const float* tfp = tf + h * 64 + kg * 8;
  float w[8], eu[8], num[8], den[8];
  int sb = ((c * B_ + b) * H_ + h) * 64 + kg * 8;
  float4 n0 = *(const float4*)(prefN + sb), n1 = *(const float4*)(prefN + sb + 4);
  float4 d0 = *(const float4*)(prefD + sb), d1 = *(const float4*)(prefD + sb + 4);
  num[0]=n0.x; num[1]=n0.y; num[2]=n0.z; num[3]=n0.w;
  num[4]=n1.x; num[5]=n1.y; num[6]=n1.z; num[7]=n1.w;
  den[0]=d0.x; den[1]=d0.y; den[2]=d0.z; den[3]=d0.w;
  den[4]=d1.x; den[5]=d1.y; den[6]=d1.z; den[7]=d1.w;
#pragma unroll
  for (int j = 0; j < 8; ++j) {
    w[j]  = __expf(-__expf(tdp[j]));
    eu[j] = __expf(tfp[j]);
  }
  size_t base = ((size_t)(b * T_ + c * CLEN)) * D_ + h * 64 + kg * 8;
  float s1 = 0.f, s2 = 0.f;
#pragma unroll 4
  for (int i = 0; i < CLEN; ++i) {
    size_t idx = base + (size_t)i * D_;
    bf16x8 k8 = *(const bf16x8*)(Kb + idx);
    bf16x8 v8 = *(const bf16x8*)(Vb + idx);
    bf16x8 r8 = *(const bf16x8*)(RY + idx);
    bf16x8 y8;
#pragma unroll
    for (int j = 0; j < 8; ++j) {
      float kk = bf2f((unsigned short)k8[j]);
      float vv = bf2f((unsigned short)v8[j]);
      float rr = bf2f((unsigned short)r8[j]);
      float ek = __expf(kk);
      float wkv = __fdividef(num[j] + eu[j] * ek * vv, den[j] + eu[j] * ek + 1e-9f);
      unsigned short ybf = f2bf(rr * wkv);
      y8[j] = (short)ybf;
      float y = bf2f(ybf);                 // stats on the stored (rounded) value
      s1 += y; s2 += y * y;
      num[j] = num[j] * w[j] + ek * vv;
      den[j] = den[j] * w[j] + ek;
    }
    *(bf16x8*)(RY + idx) = y8;
  }
  // reduce over the 8 lanes covering one head (kg = 0..7 are consecutive lanes)
#pragma unroll
  for (int off = 4; off; off >>= 1) {
    s1 += __shfl_xor(s1, off);
    s2 += __shfl_xor(s2, off);
  }
  if (kg == 0) {
    atomicAdd(&gsum[b * H_ + h], s1);
    atomicAdd(&gsq [b * H_ + h], s2);
  }
}

// ---------------- GroupNorm normalize (bf16 in) + bf16 out ----------------
__global__ __launch_bounds__(256) void gn_kernel(
    const unsigned short* __restrict__ Y, const float* __restrict__ gsum,
    const float* __restrict__ gsq, const float* __restrict__ gw,
    const float* __restrict__ gb, unsigned short* __restrict__ Ybf) {
  size_t gid = (size_t)blockIdx.x * 256 + threadIdx.x;
  size_t idx4 = gid * 4;
  int d = (int)(idx4 % D_);
  size_t row = idx4 / D_;
  int b = (int)(row >> 12);          // T = 4096
  int h = d >> 6;
  int g = b * H_ + h;
  const float inv = 1.f / (float)(T_ * 64);
  float mean = gsum[g] * inv;
  float var = gsq[g] * inv - mean * mean;
  float rstd = rsqrtf(var + 1e-5f);
  ushort4 yu = *(const ushort4*)(Y + idx4);
  float4 wv = *(const float4*)(gw + d);
  float4 bv = *(const float4*)(gb + d);
  ushort4 o;
  o.x = f2bf((bf2f(yu.x) - mean) * rstd * wv.x + bv.x);
  o.y = f2bf((bf2f(yu.y) - mean) * rstd * wv.y + bv.y);
  o.z = f2bf((bf2f(yu.z) - mean) * rstd * wv.z + bv.z);
  o.w = f2bf((bf2f(yu.w) - mean) * rstd * wv.w + bv.w);
  *(ushort4*)(Ybf + idx4) = o;
}

extern "C" void kernel_launch(void* const* d_in, const int* in_sizes, int n_in,
                              void* d_out, int out_size, void* d_ws, size_t ws_size,
                              hipStream_t stream) {
  (void)in_sizes; (void)n_in;
  const float* x   = (const float*)d_in[0];
  const float* tmr = (const float*)d_in[1];
  const float* tmk = (const float*)d_in[2];
  const float* tmv = (const float*)d_in[3];
  const float* td  = (const float*)d_in[4];
  const float* tf  = (const float*)d_in[5];
  const float* Wr  = (const float*)d_in[6];
  const float* Wk  = (const float*)d_in[7];
  const float* Wv  = (const float*)d_in[8];
  const float* Wo  = (const float*)d_in[9];
  const float* gw  = (const float*)d_in[10];
  const float* gb  = (const float*)d_in[11];
  float* out = (float*)d_out;

  constexpr size_t MD = (size_t)M_ * D_;
  constexpr size_t NEED = 4 * (MD * 2)              // XR, XK, XV, Rb (bf16)
                        + (size_t)4 * WELEM * 2     // Wb
                        + 4 * ((size_t)CHUNKS * NCH * 4)  // sumN/sumD/prefN/prefD
                        + 1024;                     // gstats
  if (ws_size < NEED) {
    // diagnostic fallback: ws too small — produce zeros instead of faulting
    zero_out_kernel<<<(int)((MD / 4 + 255) / 256), 256, 0, stream>>>(out, MD / 4);
    return;
  }

  char* ws = (char*)d_ws;
  unsigned short* XR = (unsigned short*)ws; ws += MD * 2;
  unsigned short* XK = (unsigned short*)ws; ws += MD * 2;
  unsigned short* XV = (unsigned short*)ws; ws += MD * 2;
  unsigned short* Rb = (unsigned short*)ws; ws += MD * 2;
  unsigned short* Wb = (unsigned short*)ws; ws += (size_t)4 * WELEM * 2;
  float* sumN  = (float*)ws; ws += (size_t)CHUNKS * NCH * 4;
  float* sumD  = (float*)ws; ws += (size_t)CHUNKS * NCH * 4;
  float* prefN = (float*)ws; ws += (size_t)CHUNKS * NCH * 4;
  float* prefD = (float*)ws; ws += (size_t)CHUNKS * NCH * 4;
  float* gstats = (float*)ws; ws += 1024;
  // aliases onto dead buffers (dataflow-checked):
  unsigned short* Kb = XR;   // XR dead after gemm-r
  unsigned short* Vb = XK;   // XK dead after gemm-k
  unsigned short* Yb = XV;   // XV dead after gemm-v

  mix_kernel<<<(int)(MD / 1024), 256, 0, stream>>>(x, tmr, tmk, tmv, XR, XK, XV);
  wconv_kernel<<<(4 * WELEM / 4) / 256, 256, 0, stream>>>(Wr, Wk, Wv, Wo, Wb);

  dim3 ggrid(D_ / 128, M_ / 128);
  gemm_nt<1, 1><<<ggrid, 256, 0, stream>>>(XR, Wb,             Rb, M_, D_, D_);
  gemm_nt<0, 1><<<ggrid, 256, 0, stream>>>(XK, Wb + WELEM,     Kb, M_, D_, D_);
  gemm_nt<0, 1><<<ggrid, 256, 0, stream>>>(XV, Wb + 2 * WELEM, Vb, M_, D_, D_);

  wkv_pass1<<<(CHUNKS * NCH / 8) / 256, 256, 0, stream>>>(Kb, Vb, td, sumN, sumD);
  wkv_pass2<<<192, 256, 0, stream>>>(sumN, sumD, td, prefN, prefD, gstats);
  wkv_pass3<<<(CHUNKS * NCH / 8) / 256, 256, 0, stream>>>(Kb, Vb, Rb, td, tf,
                                                          prefN, prefD, gstats, gstats + 96);
  gn_kernel<<<(int)(MD / 1024), 256, 0, stream>>>(Rb, gstats, gstats + 96, gw, gb, Yb);

  gemm_nt<0, 0><<<ggrid, 256, 0, stream>>>(Yb, Wb + 3 * WELEM, out, M_, D_, D_);
}

// Round 4
// 515.767 us; speedup vs baseline: 1.1089x; 1.0443x over previous
//
#include <hip/hip_runtime.h>
#include <hip/hip_bf16.h>
#include <cstdint>

#define B_ 8
#define T_ 4096
#define D_ 768
#define H_ 12
#define M_ (B_*T_)          // 32768 rows
#define CHUNKS 256
#define CLEN 16             // CHUNKS*CLEN == T_
#define WELEM (D_*D_)       // 589824
#define NCH (B_*H_*64)      // 6144 scan channels

typedef __attribute__((ext_vector_type(8))) short bf16x8;
typedef __attribute__((ext_vector_type(4))) float f32x4;

static __device__ __forceinline__ unsigned short f2bf(float f) {
  __hip_bfloat16 h = __float2bfloat16(f);
  return __builtin_bit_cast(unsigned short, h);
}
static __device__ __forceinline__ float bf2f(unsigned short u) {
  unsigned v = ((unsigned)u) << 16;
  return __builtin_bit_cast(float, v);
}

static __device__ __forceinline__ void async16(const void* g, void* l) {
  __builtin_amdgcn_global_load_lds(
      (const __attribute__((address_space(1))) unsigned int*)g,
      (__attribute__((address_space(3))) unsigned int*)l, 16, 0, 0);
}

// ---------------- fallback: zero the output (ws too small diagnostic) ----------------
__global__ __launch_bounds__(256) void zero_out_kernel(float* __restrict__ out, size_t n4) {
  size_t gid = (size_t)blockIdx.x * 256 + threadIdx.x;
  if (gid < n4) *(float4*)(out + gid * 4) = make_float4(0.f, 0.f, 0.f, 0.f);
}

// ---------------- token-shift mix: xr/xk/xv (bf16) ----------------
__global__ __launch_bounds__(256) void mix_kernel(
    const float* __restrict__ x, const float* __restrict__ tmr,
    const float* __restrict__ tmk, const float* __restrict__ tmv,
    unsigned short* __restrict__ xr, unsigned short* __restrict__ xk,
    unsigned short* __restrict__ xv) {
  size_t gid = (size_t)blockIdx.x * 256 + threadIdx.x;
  size_t idx4 = gid * 4;
  int d = (int)(idx4 % D_);
  size_t row = idx4 / D_;
  int t = (int)(row & (T_ - 1));
  float4 xc = *(const float4*)(x + idx4);
  float4 xp = make_float4(0.f, 0.f, 0.f, 0.f);
  if (t > 0) xp = *(const float4*)(x + idx4 - D_);
  float4 mr = *(const float4*)(tmr + d);
  float4 mk = *(const float4*)(tmk + d);
  float4 mv = *(const float4*)(tmv + d);
  ushort4 orr, okk, ovv;
  orr.x = f2bf(xc.x*mr.x + xp.x*(1.f-mr.x));
  orr.y = f2bf(xc.y*mr.y + xp.y*(1.f-mr.y));
  orr.z = f2bf(xc.z*mr.z + xp.z*(1.f-mr.z));
  orr.w = f2bf(xc.w*mr.w + xp.w*(1.f-mr.w));
  okk.x = f2bf(xc.x*mk.x + xp.x*(1.f-mk.x));
  okk.y = f2bf(xc.y*mk.y + xp.y*(1.f-mk.y));
  okk.z = f2bf(xc.z*mk.z + xp.z*(1.f-mk.z));
  okk.w = f2bf(xc.w*mk.w + xp.w*(1.f-mk.w));
  ovv.x = f2bf(xc.x*mv.x + xp.x*(1.f-mv.x));
  ovv.y = f2bf(xc.y*mv.y + xp.y*(1.f-mv.y));
  ovv.z = f2bf(xc.z*mv.z + xp.z*(1.f-mv.z));
  ovv.w = f2bf(xc.w*mv.w + xp.w*(1.f-mv.w));
  *(ushort4*)(xr + idx4) = orr;
  *(ushort4*)(xk + idx4) = okk;
  *(ushort4*)(xv + idx4) = ovv;
}

// ---------------- weight fp32 -> bf16 (3 matrices: Wr, Wk, Wv) ----------------
__global__ __launch_bounds__(256) void wconv_kernel(
    const float* __restrict__ a, const float* __restrict__ b,
    const float* __restrict__ c, unsigned short* __restrict__ o) {
  size_t gid = (size_t)blockIdx.x * 256 + threadIdx.x;
  size_t idx4 = gid * 4;
  size_t mi = idx4 / WELEM;
  size_t off = idx4 % WELEM;
  const float* src = (mi == 0) ? a : (mi == 1) ? b : c;
  float4 v = *(const float4*)(src + off);
  ushort4 u;
  u.x = f2bf(v.x); u.y = f2bf(v.y); u.z = f2bf(v.z); u.w = f2bf(v.w);
  *(ushort4*)(o + idx4) = u;
}

// ---- GEMM: C[M,768] = A[M,768] @ Bw[768,768]^T. ACT: 1=sigmoid. OBF: 1=bf16 out.
// BIAS: B selected per batch (Wo_b[b]) + bias2[b][n] added (GN folded into GEMM).
// m97 regime: 128x128 tile, BK=32, 2-stage dbuf in 32 KB LDS -> 3 blocks/CU
// (launch_bounds (256,3)); stage-next-early + syncthreads; XOR-swizzled LDS;
// XCD-chunked block swizzle; LDS-staged bf16 epilogue for full-line writes.
template<int ACT, int OBF, int BIAS>
__global__ __launch_bounds__(256, 3) void gemm_nt(
    const unsigned short* __restrict__ A,
    const unsigned short* __restrict__ Bw,
    void* __restrict__ Cv, const float* __restrict__ bias2) {
  __shared__ __align__(16) unsigned short smem[128 * 128];   // 32 KB total
  const int tid = threadIdx.x;
  const int wave = tid >> 6, lane = tid & 63;
  const int quad = lane >> 4, l16 = lane & 15;

  // XCD-aware chunked swizzle (bijective even when nwg % 8 != 0)
  int nwg = gridDim.x * gridDim.y;
  int lin = blockIdx.y * gridDim.x + blockIdx.x;
  int q = nwg >> 3, r = nwg & 7;
  int xcd = lin & 7, off = lin >> 3;
  int swz = (xcd < r ? xcd * (q + 1) : r * (q + 1) + (xcd - r) * q) + off;
  const int m0 = (swz / gridDim.x) * 128;
  const int n0 = (swz % gridDim.x) * 128;
  const int wm = (wave & 1) * 64, wn = (wave >> 1) * 64;
  const int bb = m0 >> 12;                 // batch index (blocks never straddle)
  const unsigned short* Bp = BIAS ? Bw + (size_t)bb * WELEM : Bw;

  // stage one BK=32 tile (A:128x32 + B:128x32 bf16 = 16 KB) into stage buf.
  auto stage = [&](int buf, int kb) {
    unsigned short* Ls = smem + buf * (128 * 64);
#pragma unroll
    for (int j = 0; j < 2; ++j) {
      int chunk = j * 256 + tid;           // 0..511 16B-granules
      int row = chunk >> 2, slot = chunk & 3;
      int ks = slot ^ ((row >> 1) & 3);    // pre-swizzled global source granule
      async16(A  + ((size_t)(m0 + row)) * D_ + kb + ks * 8, &Ls[chunk * 8]);
      async16(Bp + ((size_t)(n0 + row)) * D_ + kb + ks * 8, &Ls[128 * 32 + chunk * 8]);
    }
  };

  f32x4 acc[4][4] = {};
  const int NT = D_ / 32;                  // 24 K-tiles

  stage(0, 0);
  __syncthreads();                         // buf0 ready
  int cur = 0;
  for (int t = 0; t < NT; ++t) {
    if (t + 1 < NT) stage(cur ^ 1, (t + 1) * 32);   // issue next tile EARLY
    const unsigned short* As = smem + cur * (128 * 64);
    const unsigned short* Bs = As + 128 * 32;
    bf16x8 a[4], b[4];
#pragma unroll
    for (int i = 0; i < 4; ++i) {
      int ra = wm + i * 16 + l16;
      a[i] = *(const bf16x8*)&As[ra * 32 + ((quad ^ ((ra >> 1) & 3)) * 8)];
      int rb = wn + i * 16 + l16;
      b[i] = *(const bf16x8*)&Bs[rb * 32 + ((quad ^ ((rb >> 1) & 3)) * 8)];
    }
#pragma unroll
    for (int i = 0; i < 4; ++i)
#pragma unroll
      for (int jj = 0; jj < 4; ++jj)
        acc[i][jj] = __builtin_amdgcn_mfma_f32_16x16x32_bf16(a[i], b[jj], acc[i][jj], 0, 0, 0);
    __syncthreads();                       // next buf ready; cur reads done
    cur ^= 1;
  }

  if (OBF) {
    // LDS-staged epilogue: full 64B-line ushort8 stores
    unsigned short* Cs = smem;             // [128][128] bf16, granule-XOR swizzled
#pragma unroll
    for (int i = 0; i < 4; ++i) {
#pragma unroll
      for (int jj = 0; jj < 4; ++jj) {
        int col = wn + jj * 16 + l16;
#pragma unroll
        for (int rr = 0; rr < 4; ++rr) {
          int row = wm + i * 16 + quad * 4 + rr;
          float v = acc[i][jj][rr];
          if (ACT == 1) v = 1.f / (1.f + __expf(-v));
          int cg = (col >> 3) ^ (row & 7);
          Cs[row * 128 + cg * 8 + (col & 7)] = f2bf(v);
        }
      }
    }
    __syncthreads();
#pragma unroll
    for (int g = 0; g < 8; ++g) {
      int gi = g * 256 + tid;              // 0..2047: 128 rows x 16 granules
      int row = gi >> 4, cg = gi & 15;
      int sg = cg ^ (row & 7);
      bf16x8 vv = *(const bf16x8*)&Cs[row * 128 + sg * 8];
      *(bf16x8*)((unsigned short*)Cv + (size_t)(m0 + row) * D_ + n0 + cg * 8) = vv;
    }
  } else {
    // fp32 out (+ per-batch GN bias when BIAS): quad-row 64B segments = full lines
#pragma unroll
    for (int i = 0; i < 4; ++i) {
      int rowb = m0 + wm + i * 16 + quad * 4;
#pragma unroll
      for (int jj = 0; jj < 4; ++jj) {
        int col = n0 + wn + jj * 16 + l16;
        float bias = BIAS ? bias2[bb * D_ + col] : 0.f;
#pragma unroll
        for (int rr = 0; rr < 4; ++rr) {
          float v = acc[i][jj][rr] + bias;
          ((float*)Cv)[(size_t)(rowb + rr) * D_ + col] = v;
        }
      }
    }
  }
}

// ---------------- WKV pass 1: per-chunk local scan, 8 channels/thread ----------------
__global__ __launch_bounds__(256) void wkv_pass1(
    const unsigned short* __restrict__ Kb, const unsigned short* __restrict__ Vb,
    const float* __restrict__ td,
    float* __restrict__ sumN, float* __restrict__ sumD) {
  int gid = blockIdx.x * 256 + threadIdx.x;   // ((c*B + b)*H + h)*8 + kg
  int kg = gid & 7;
  int tmp = gid >> 3;
  int h = tmp % H_;
  tmp /= H_;
  int b = tmp % B_;
  int c = tmp / B_;
  const float* tdp = td + h * 64 + kg * 8;
  float w[8], num[8], den[8];
#pragma unroll
  for (int j = 0; j < 8; ++j) {
    w[j] = __expf(-__expf(tdp[j]));
    num[j] = 0.f; den[j] = 0.f;
  }
  size_t base = ((size_t)(b * T_ + c * CLEN)) * D_ + h * 64 + kg * 8;
#pragma unroll 4
  for (int i = 0; i < CLEN; ++i) {
    bf16x8 k8 = *(const bf16x8*)(Kb + base + (size_t)i * D_);
    bf16x8 v8 = *(const bf16x8*)(Vb + base + (size_t)i * D_);
#pragma unroll
    for (int j = 0; j < 8; ++j) {
      float ek = __expf(bf2f((unsigned short)k8[j]));
      num[j] = num[j] * w[j] + ek * bf2f((unsigned short)v8[j]);
      den[j] = den[j] * w[j] + ek;
    }
  }
  int ob = ((c * B_ + b) * H_ + h) * 64 + kg * 8;
  *(float4*)(sumN + ob)     = make_float4(num[0], num[1], num[2], num[3]);
  *(float4*)(sumN + ob + 4) = make_float4(num[4], num[5], num[6], num[7]);
  *(float4*)(sumD + ob)     = make_float4(den[0], den[1], den[2], den[3]);
  *(float4*)(sumD + ob + 4) = make_float4(den[4], den[5], den[6], den[7]);
}

// ------- WKV pass 2: inter-chunk exclusive prefix — coalesced LDS-transposed scan -------
__global__ __launch_bounds__(256) void wkv_pass2(
    const float* __restrict__ sumN, const float* __restrict__ sumD,
    const float* __restrict__ td,
    float* __restrict__ prefN, float* __restrict__ prefD,
    float* __restrict__ gstats) {
  __shared__ float tile[256][64];           // 64KB
  int bid = blockIdx.x;                     // [0,192)
  if (bid == 0 && threadIdx.x < 192) gstats[threadIdx.x] = 0.f;
  int bh = bid >> 1, qd = bid & 1;
  const float* src = qd ? sumD : sumN;
  float* dst = qd ? prefD : prefN;
  int h = bh % H_;
  int base = bh * 64;                       // channel base within NCH
  int t = threadIdx.x;
  { // load: 16 rows x float4 per thread, coalesced
    int c4 = (t & 15) * 4;
    int rg = t >> 4;
#pragma unroll 4
    for (int i = 0; i < 16; ++i) {
      int row = rg * 16 + i;
      *(float4*)&tile[row][c4] = *(const float4*)&src[(size_t)row * NCH + base + c4];
    }
  }
  __syncthreads();
  int ch = t & 63, g = t >> 6;              // 4 groups x 64 rows
  float w = __expf(-__expf(td[h * 64 + ch]));
  float wL = w;
#pragma unroll
  for (int i = 0; i < 4; ++i) wL *= wL;     // w^16 (= w^CLEN)
  // serial inclusive scan within group, in place
  float v = 0.f;
  for (int i = 0; i < 64; ++i) {
    int row = g * 64 + i;
    v = v * wL + tile[row][ch];
    tile[row][ch] = v;
  }
  __syncthreads();
  // cross-group carry E_g
  float wL64 = wL;
#pragma unroll
  for (int i = 0; i < 6; ++i) wL64 *= wL64; // wL^64
  float E = 0.f;
  for (int gp = 0; gp < g; ++gp)            // g is wave-uniform
    E = E * wL64 + tile[gp * 64 + 63][ch];
  float f = 1.f;
  for (int i = 0; i < 64; ++i) {
    int row = g * 64 + i;
    float P = (i == 0) ? E : tile[row - 1][ch] + E * f;
    dst[(size_t)row * NCH + base + ch] = P;
    f *= wL;
  }
}

// --- WKV pass 3: wkv + y=r*wkv (in-place over r, bf16) + GN partial sums; 8 ch/thread ---
__global__ __launch_bounds__(256) void wkv_pass3(
    const unsigned short* __restrict__ Kb, const unsigned short* __restrict__ Vb,
    unsigned short* __restrict__ RY,
    const float* __restrict__ td, const float* __restrict__ tf,
    const float* __restrict__ prefN, const float* __restrict__ prefD,
    float* __restrict__ gsum, float* __restrict__ gsq) {
  int gid = blockIdx.x * 256 + threadIdx.x;   // ((c*B + b)*H + h)*8 + kg
  int kg = gid & 7;
  int tmp = gid >> 3;
  int h = tmp % H_;
  tmp /= H_;
  int b = tmp % B_;
  int c = tmp / B_;
  const float* tdp = td + h * 64 + kg * 8;
  const float* tfp = tf + h * 64 + kg * 8;
  float w[8], eu[8], num[8], den[8];
  int sb = ((c * B_ + b) * H_ + h) * 64 + kg * 8;
  float4 n0 = *(const float4*)(prefN + sb), n1 = *(const float4*)(prefN + sb + 4);
  float4 d0 = *(const float4*)(prefD + sb), d1 = *(const float4*)(prefD + sb + 4);
  num[0]=n0.x; num[1]=n0.y; num[2]=n0.z; num[3]=n0.w;
  num[4]=n1.x; num[5]=n1.y; num[6]=n1.z; num[7]=n1.w;
  den[0]=d0.x; den[1]=d0.y; den[2]=d0.z; den[3]=d0.w;
  den[4]=d1.x; den[5]=d1.y; den[6]=d1.z; den[7]=d1.w;
#pragma unroll
  for (int j = 0; j < 8; ++j) {
    w[j]  = __expf(-__expf(tdp[j]));
    eu[j] = __expf(tfp[j]);
  }
  size_t base = ((size_t)(b * T_ + c * CLEN)) * D_ + h * 64 + kg * 8;
  float s1 = 0.f, s2 = 0.f;
#pragma unroll 4
  for (int i = 0; i < CLEN; ++i) {
    size_t idx = base + (size_t)i * D_;
    bf16x8 k8 = *(const bf16x8*)(Kb + idx);
    bf16x8 v8 = *(const bf16x8*)(Vb + idx);
    bf16x8 r8 = *(const bf16x8*)(RY + idx);
    bf16x8 y8;
#pragma unroll
    for (int j = 0; j < 8; ++j) {
      float kk = bf2f((unsigned short)k8[j]);
      float vv = bf2f((unsigned short)v8[j]);
      float rr = bf2f((unsigned short)r8[j]);
      float ek = __expf(kk);
      float wkv = __fdividef(num[j] + eu[j] * ek * vv, den[j] + eu[j] * ek + 1e-9f);
      unsigned short ybf = f2bf(rr * wkv);
      y8[j] = (short)ybf;
      float y = bf2f(ybf);                 // stats on the stored (rounded) value
      s1 += y; s2 += y * y;
      num[j] = num[j] * w[j] + ek * vv;
      den[j] = den[j] * w[j] + ek;
    }
    *(bf16x8*)(RY + idx) = y8;
  }
#pragma unroll
  for (int off = 4; off; off >>= 1) {
    s1 += __shfl_xor(s1, off);
    s2 += __shfl_xor(s2, off);
  }
  if (kg == 0) {
    atomicAdd(&gsum[b * H_ + h], s1);
    atomicAdd(&gsq [b * H_ + h], s2);
  }
}

// ------- Wo scaling: Wo_b[b][n][d] = bf16(Wo[n][d] * rstd[b,h(d)] * gw[d]) -------
__global__ __launch_bounds__(256) void woprep_kernel(
    const float* __restrict__ Wo, const float* __restrict__ gsum,
    const float* __restrict__ gsq, const float* __restrict__ gw,
    unsigned short* __restrict__ Wob) {
  int blk = blockIdx.x;                    // 8 * 576
  int b = blk / (WELEM / 1024);
  size_t off = (size_t)(blk % (WELEM / 1024)) * 1024 + threadIdx.x * 4;
  int d = (int)(off % D_);                 // d..d+3 in same head (d%4==0)
  int g = b * H_ + (d >> 6);
  const float inv = 1.f / (float)(T_ * 64);
  float mean = gsum[g] * inv;
  float var = gsq[g] * inv - mean * mean;
  float rstd = rsqrtf(var + 1e-5f);
  float4 wo = *(const float4*)(Wo + off);
  float4 gwv = *(const float4*)(gw + d);
  ushort4 o;
  o.x = f2bf(wo.x * rstd * gwv.x);
  o.y = f2bf(wo.y * rstd * gwv.y);
  o.z = f2bf(wo.z * rstd * gwv.z);
  o.w = f2bf(wo.w * rstd * gwv.w);
  *(ushort4*)(Wob + (size_t)b * WELEM + off) = o;
}

// ------- bias2[b][n] = sum_d (gb[d] - mean*rstd*gw[d]) * Wo[n][d] -------
__global__ __launch_bounds__(256) void bias2_kernel(
    const float* __restrict__ Wo, const float* __restrict__ gsum,
    const float* __restrict__ gsq, const float* __restrict__ gw,
    const float* __restrict__ gb, float* __restrict__ bias2) {
  int blk = blockIdx.x;                    // 96 = 8 b x 12 nchunks
  int b = blk / 12, nb = (blk % 12) * 64;
  int lane = threadIdx.x & 63, wv = threadIdx.x >> 6;
  const float inv = 1.f / (float)(T_ * 64);
  float cB[12];
#pragma unroll
  for (int j = 0; j < 12; ++j) {
    int d = lane + 64 * j;                 // head(d) == j
    int g = b * H_ + j;
    float mean = gsum[g] * inv;
    float var = gsq[g] * inv - mean * mean;
    float rstd = rsqrtf(var + 1e-5f);
    cB[j] = gb[d] - mean * rstd * gw[d];
  }
  for (int n = nb + wv * 16, e = n + 16; n < e; ++n) {
    float s = 0.f;
#pragma unroll
    for (int j = 0; j < 12; ++j)
      s += cB[j] * Wo[(size_t)n * D_ + lane + 64 * j];
#pragma unroll
    for (int off = 32; off; off >>= 1) s += __shfl_down(s, off);
    if (lane == 0) bias2[b * D_ + n] = s;
  }
}

extern "C" void kernel_launch(void* const* d_in, const int* in_sizes, int n_in,
                              void* d_out, int out_size, void* d_ws, size_t ws_size,
                              hipStream_t stream) {
  (void)in_sizes; (void)n_in;
  const float* x   = (const float*)d_in[0];
  const float* tmr = (const float*)d_in[1];
  const float* tmk = (const float*)d_in[2];
  const float* tmv = (const float*)d_in[3];
  const float* td  = (const float*)d_in[4];
  const float* tf  = (const float*)d_in[5];
  const float* Wr  = (const float*)d_in[6];
  const float* Wk  = (const float*)d_in[7];
  const float* Wv  = (const float*)d_in[8];
  const float* Wo  = (const float*)d_in[9];
  const float* gw  = (const float*)d_in[10];
  const float* gb  = (const float*)d_in[11];
  float* out = (float*)d_out;

  constexpr size_t MD = (size_t)M_ * D_;
  constexpr size_t NEED = 4 * (MD * 2)              // XR, XK, XV, Rb (bf16)
                        + (size_t)4 * WELEM * 2     // Wb
                        + 4 * ((size_t)CHUNKS * NCH * 4)  // sumN/sumD/prefN/prefD
                        + 1024;                     // gstats
  if (ws_size < NEED) {
    zero_out_kernel<<<(int)((MD / 4 + 255) / 256), 256, 0, stream>>>(out, MD / 4);
    return;
  }

  char* ws = (char*)d_ws;
  unsigned short* XR = (unsigned short*)ws; ws += MD * 2;
  unsigned short* XK = (unsigned short*)ws; ws += MD * 2;
  unsigned short* XV = (unsigned short*)ws; ws += MD * 2;
  unsigned short* Rb = (unsigned short*)ws; ws += MD * 2;
  unsigned short* Wb = (unsigned short*)ws; ws += (size_t)4 * WELEM * 2;
  float* sumN  = (float*)ws; ws += (size_t)CHUNKS * NCH * 4;
  float* sumD  = (float*)ws; ws += (size_t)CHUNKS * NCH * 4;
  float* prefN = (float*)ws; ws += (size_t)CHUNKS * NCH * 4;
  float* prefD = (float*)ws; ws += (size_t)CHUNKS * NCH * 4;
  float* gstats = (float*)ws; ws += 1024;
  // aliases onto dead buffers (dataflow-checked):
  unsigned short* Kb = XR;                     // XR dead after gemm-r
  unsigned short* Vb = XK;                     // XK dead after gemm-k
  unsigned short* Wob = (unsigned short*)sumN; // sumN+sumD dead after pass2 (9.4MB <= 12.6MB)
  float* bias2 = prefN;                        // prefN dead after pass3

  mix_kernel<<<(int)(MD / 1024), 256, 0, stream>>>(x, tmr, tmk, tmv, XR, XK, XV);
  wconv_kernel<<<(3 * WELEM / 4) / 256, 256, 0, stream>>>(Wr, Wk, Wv, Wb);

  dim3 ggrid(D_ / 128, M_ / 128);
  gemm_nt<1, 1, 0><<<ggrid, 256, 0, stream>>>(XR, Wb,             Rb, nullptr);
  gemm_nt<0, 1, 0><<<ggrid, 256, 0, stream>>>(XK, Wb + WELEM,     Kb, nullptr);
  gemm_nt<0, 1, 0><<<ggrid, 256, 0, stream>>>(XV, Wb + 2 * WELEM, Vb, nullptr);

  wkv_pass1<<<(CHUNKS * NCH / 8) / 256, 256, 0, stream>>>(Kb, Vb, td, sumN, sumD);
  wkv_pass2<<<192, 256, 0, stream>>>(sumN, sumD, td, prefN, prefD, gstats);
  wkv_pass3<<<(CHUNKS * NCH / 8) / 256, 256, 0, stream>>>(Kb, Vb, Rb, td, tf,
                                                          prefN, prefD, gstats, gstats + 96);

  // GN folded into output GEMM: Wo_b = Wo * (rstd*gw) per batch; bias2 = cB @ Wo^T
  woprep_kernel<<<8 * (WELEM / 1024), 256, 0, stream>>>(Wo, gstats, gstats + 96, gw, Wob);
  bias2_kernel<<<96, 256, 0, stream>>>(Wo, gstats, gstats + 96, gw, gb, bias2);

  gemm_nt<0, 0, 1><<<ggrid, 256, 0, stream>>>(Rb, Wob, out, bias2);
}